// Round 8
// baseline (236.217 us; speedup 1.0000x reference)
//
#include <hip/hip_runtime.h>
#include <math.h>

#define TOKENS 16384
#define HIDDEN 2048
#define NEXP   64
#define MT     16                  // tokens per block (= per wave)
#define NBLK   (TOKENS / MT)       // 1024
#define BK     256                 // k floats per chunk
#define NCH    (HIDDEN / BK)       // 8
#define CB     16384               // bytes per LDS chunk buffer (16 rows x 1KB)

#define GATES_OFF (TOKENS * 2)
#define SEL_OFF   (GATES_OFF + TOKENS * NEXP)
#define Z_OFF     (SEL_OFF + TOKENS * 2)

#define WIMG_BYTES (NEXP * HIDDEN * 2 * 2)   // 512 KB fp16 wh+wl fragment image

typedef __attribute__((ext_vector_type(8))) _Float16 f16x8;
typedef __attribute__((ext_vector_type(4))) float    f32x4;

__device__ __forceinline__ float wave_sum64(float v) {
    #pragma unroll
    for (int s = 1; s < 64; s <<= 1) v += __shfl_xor(v, s, 64);
    return v;
}

// direct global->LDS DMA, 16 B per lane (dest = uniform base + lane*16)
__device__ __forceinline__ void dma16(const void* g, void* l) {
    __builtin_amdgcn_global_load_lds(
        (const __attribute__((address_space(1))) unsigned int*)g,
        (__attribute__((address_space(3))) unsigned int*)l, 16, 0, 0);
}

// ---------------------------------------------------------------------------
// Setup: w [64,2048] fp32 -> fp16 (hi, lo*4096) fragment image. [verified R3]
// ---------------------------------------------------------------------------
__global__ __launch_bounds__(256) void wconvert(
    const float* __restrict__ w, uint4* __restrict__ wimg)
{
    const int s = blockIdx.x * 256 + threadIdx.x;     // 0..32767
    const int c    = s >> 10;
    const int r    = s & 1023;
    const int l    = r & 63;
    const int nt   = (r >> 6) & 1;
    const int kh   = (r >> 7) & 1;
    const int term = (r >> 8) & 1;
    const int eh   = (r >> 9) & 1;
    const int e = eh * 32 + nt * 16 + (l & 15);
    const int k = c * 64 + kh * 32 + (l >> 4) * 8;

    const float* src = w + (size_t)e * HIDDEN + k;
    union { _Float16 f[8]; uint4 u; } o;
    #pragma unroll
    for (int j = 0; j < 8; ++j) {
        const float v = src[j];
        const _Float16 h = (_Float16)v;
        o.f[j] = (term == 0) ? h : (_Float16)((v - (float)h) * 4096.f);
    }
    wimg[s] = o.u;
}

// fp32 -> (hi, lo*4096) fp16x8 split of 8 floats [verified R3]
__device__ __forceinline__ void cvt_split(const float4 a, const float4 b,
                                          f16x8& hi, f16x8& lo) {
    union { _Float16 f[8]; f16x8 v; } H, L;
    #pragma unroll
    for (int j = 0; j < 4; ++j) {
        const float s0 = (&a.x)[j];
        const float s1 = (&b.x)[j];
        const _Float16 h0 = (_Float16)s0;
        const _Float16 h1 = (_Float16)s1;
        H.f[j]     = h0;
        H.f[j + 4] = h1;
        L.f[j]     = (_Float16)((s0 - (float)h0) * 4096.f);
        L.f[j + 4] = (_Float16)((s1 - (float)h1) * 4096.f);
    }
    hi = H.v; lo = L.v;
}

// ---------------------------------------------------------------------------
// R8: wave-synchronous zero-barrier router.
// R7 post-mortem: per-chunk __syncthreads (vmcnt(0) drain, block-wide) still
// exposed a full memory round trip x8 -> router ~73us vs 21us HBM roofline.
// Fix: 1024 blocks of ONE wave (64 thr). Wave owns 16 tokens x 64 experts x
// full K; x staged to PRIVATE LDS (2 x 16KB dbuf) via global_load_lds. No
// s_barrier anywhere: buffer readiness = same-wave s_waitcnt vmcnt(0) at the
// TOP of body c (DMA(c) was issued one full chunk of compute ago -> wait is
// free), then DMA(c+1) issues and flies under body c's ~1100cyc of compute.
// LDS layout [kblk][row][16B]: DMA dest base+lane*16 maps lane->(kblk=l>>4,
// row=l&15) with ONE fixed per-lane global offset (row*8192 + (l>>4)*16 B);
// no swizzle, MFMA-step reads <=2-way bank aliased by construction.
// Epilogue fully in-register: C-layout puts token t's 64 experts in lane
// group t>>2 (4 vals/lane, e = g*16 + (lane&15)); 4 tokens route in parallel
// via width-16 shuffle reductions (R1-verified math, verified tie-break
// order preserved: e increases with g). z via zpartial + zfinal.
// ---------------------------------------------------------------------------
__global__ __launch_bounds__(64) void router_main(
    const float* __restrict__ x, const uint4* __restrict__ wimg,
    float* __restrict__ out, float* __restrict__ zpartial)
{
    __shared__ __align__(16) unsigned char smem[2 * CB];   // 32 KB, wave-private

    const int lane = threadIdx.x & 63;
    const int t0   = blockIdx.x * MT;
    const int rowr = lane & 15;          // token row within tile / frag row
    const int kg   = lane >> 4;          // k-group 0..3

    // DMA source: lane l fetches row (l&15), k-bytes (l>>4)*16 of each 64B slab
    const float* xq = x + (size_t)(t0 + rowr) * HIDDEN + kg * 4;

    f32x4 acc0[4], acc1[4];
    #pragma unroll
    for (int g = 0; g < 4; ++g) { acc0[g] = (f32x4)0.f; acc1[g] = (f32x4)0.f; }

    // prologue: DMA chunk 0 into buf0 (16 calls x 1KB; call j covers k-bytes
    // [j*64, j*64+64) of all 16 rows)
    #pragma unroll
    for (int j = 0; j < 16; ++j)
        dma16(xq + j * 16, smem + j * 1024);

    for (int c = 0; c < NCH; ++c) {
        // DMA(c) issued one full chunk ago -> free wait; orders LDS reads after it
        asm volatile("s_waitcnt vmcnt(0)" ::: "memory");
        __builtin_amdgcn_sched_barrier(0);

        // issue DMA(c+1) into the other buffer; flies under this body's compute
        if (c + 1 < NCH) {
            const float* sg = xq + (c + 1) * BK;
            unsigned char* dg = smem + ((c + 1) & 1) * CB;
            #pragma unroll
            for (int j = 0; j < 16; ++j)
                dma16(sg + j * 16, dg + j * 1024);
        }

        // compute 8 MFMA steps (32 k each) from buf(c)
        const unsigned char* ab = smem + (c & 1) * CB + kg * 512 + rowr * 16;
        const uint4* wc0 = wimg + (size_t)c * 4096 + lane;
        #pragma unroll
        for (int s = 0; s < 8; ++s) {
            const uint4* p = wc0 + (s >> 1) * 1024 + (s & 1) * 128;
            f16x8 bh[4], bl[4];
            bh[0] = *(const f16x8*)(p);          // e 0..15  hi
            bh[1] = *(const f16x8*)(p + 64);     // e 16..31 hi
            bh[2] = *(const f16x8*)(p + 512);    // e 32..47 hi
            bh[3] = *(const f16x8*)(p + 576);    // e 48..63 hi
            bl[0] = *(const f16x8*)(p + 256);
            bl[1] = *(const f16x8*)(p + 320);
            bl[2] = *(const f16x8*)(p + 768);
            bl[3] = *(const f16x8*)(p + 832);

            // A: row rowr, k-floats [s*32 + kg*8, +8)  (kblk s*8+kg*2, +1)
            const float4 va = *(const float4*)(ab + s * 2048);
            const float4 vb = *(const float4*)(ab + s * 2048 + 256);
            f16x8 Ah, Al;
            cvt_split(va, vb, Ah, Al);
            #pragma unroll
            for (int g = 0; g < 4; ++g) {
                acc0[g] = __builtin_amdgcn_mfma_f32_16x16x32_f16(Ah, bh[g], acc0[g], 0, 0, 0);
                acc1[g] = __builtin_amdgcn_mfma_f32_16x16x32_f16(Ah, bl[g], acc1[g], 0, 0, 0);
                acc1[g] = __builtin_amdgcn_mfma_f32_16x16x32_f16(Al, bh[g], acc1[g], 0, 0, 0);
            }
        }
    }

    // ---- in-register routing: lane group kg handles tokens 4*kg + r.
    // C/D layout: token (lane>>4)*4 + r, expert e = g*16 + (lane&15).
    float zsum = 0.f;
    #pragma unroll
    for (int r = 0; r < 4; ++r) {
        const int t = kg * 4 + r;
        float v[4]; int e[4];
        #pragma unroll
        for (int g = 0; g < 4; ++g) {
            v[g] = acc0[g][r] + acc1[g][r] * (1.f / 4096.f);
            e[g] = g * 16 + rowr;
        }

        // pass-1 argmax (local: strict > keeps lowest g = lowest e; cross:
        // R1-verified (ov>bv)||(ov==bv&&oi<bi), width 16)
        float bv = v[0]; int bi = e[0];
        #pragma unroll
        for (int g = 1; g < 4; ++g)
            if (v[g] > bv) { bv = v[g]; bi = e[g]; }
        #pragma unroll
        for (int st = 1; st < 16; st <<= 1) {
            const float ov = __shfl_xor(bv, st, 64);
            const int   oi = __shfl_xor(bi, st, 64);
            if (ov > bv || (ov == bv && oi < bi)) { bv = ov; bi = oi; }
        }
        const float max1 = bv; const int s1 = bi;

        float e1[4], se = 0.f, sm1 = 0.f;
        #pragma unroll
        for (int g = 0; g < 4; ++g) {
            e1[g] = expf(v[g] - max1);
            se += e1[g];
            const bool m1 = (max1 - v[g]) > 0.02f * fmaxf(fabsf(v[g]), max1);
            sm1 += m1 ? 0.f : e1[g];
        }
        #pragma unroll
        for (int st = 1; st < 16; st <<= 1) {
            se  += __shfl_xor(se, st, 64);
            sm1 += __shfl_xor(sm1, st, 64);
        }

        #pragma unroll
        for (int g = 0; g < 4; ++g)
            out[GATES_OFF + (size_t)(t0 + t) * NEXP + e[g]] = e1[g] / se;

        const float lse = max1 + logf(se);
        if (rowr == 0) zsum += lse * lse;

        // pass-2 argmax with s1 masked out
        float bv2 = (e[0] == s1) ? -INFINITY : v[0]; int bi2 = e[0];
        #pragma unroll
        for (int g = 1; g < 4; ++g) {
            const float cv = (e[g] == s1) ? -INFINITY : v[g];
            if (cv > bv2) { bv2 = cv; bi2 = e[g]; }
        }
        #pragma unroll
        for (int st = 1; st < 16; st <<= 1) {
            const float ov = __shfl_xor(bv2, st, 64);
            const int   oi = __shfl_xor(bi2, st, 64);
            if (ov > bv2 || (ov == bv2 && oi < bi2)) { bv2 = ov; bi2 = oi; }
        }
        const float max2 = bv2; const int s2 = bi2;

        float sm2 = 0.f;
        #pragma unroll
        for (int g = 0; g < 4; ++g) {
            const bool m2 = (max2 - v[g]) > 0.02f * fmaxf(fabsf(v[g]), max2);
            sm2 += (m2 || e[g] == s1) ? 0.f : expf(v[g] - max2);
        }
        #pragma unroll
        for (int st = 1; st < 16; st <<= 1)
            sm2 += __shfl_xor(sm2, st, 64);

        if (rowr == 0) {
            const size_t trow = (size_t)(t0 + t) * 2;
            out[trow + 0] = 1.f / sm1;
            out[trow + 1] = 1.f / sm2;
            out[SEL_OFF + trow + 0] = (float)s1;
            out[SEL_OFF + trow + 1] = (float)s2;
        }
    }

    const float zt = wave_sum64(zsum);
    if (lane == 0) zpartial[blockIdx.x] = zt;
}

__global__ __launch_bounds__(256) void zfinal(
    const float* __restrict__ zpartial, float* __restrict__ out)
{
    const int tid = threadIdx.x;                 // 1024 partials, 256 threads
    float v = zpartial[tid] + zpartial[tid + 256]
            + zpartial[tid + 512] + zpartial[tid + 768];
    v = wave_sum64(v);
    __shared__ float red[4];
    if ((tid & 63) == 0) red[tid >> 6] = v;
    __syncthreads();
    if (tid == 0) {
        const float tot = red[0] + red[1] + red[2] + red[3];
        out[Z_OFF] = 0.001f * (tot / (float)TOKENS);
    }
}

extern "C" void kernel_launch(void* const* d_in, const int* in_sizes, int n_in,
                              void* d_out, int out_size, void* d_ws, size_t ws_size,
                              hipStream_t stream) {
    const float* x = (const float*)d_in[0];   // [16384, 2048] fp32
    const float* w = (const float*)d_in[1];   // [64, 2048] fp32
    float* out = (float*)d_out;               // mult(32768) | gates(1048576) | sel(32768) | z(1)

    uint4* wimg     = (uint4*)d_ws;                               // 512 KB
    float* zpartial = (float*)((char*)d_ws + WIMG_BYTES);         // 1024 floats

    wconvert<<<128, 256, 0, stream>>>(w, wimg);
    router_main<<<NBLK, 64, 0, stream>>>(x, wimg, out, zpartial);
    zfinal<<<1, 256, 0, stream>>>(zpartial, out);
}

// Round 9
// 221.576 us; speedup vs baseline: 1.0661x; 1.0661x over previous
//
#include <hip/hip_runtime.h>
#include <math.h>

#define TOKENS 16384
#define HIDDEN 2048
#define NEXP   64
#define MT     64                  // tokens per block (4 waves x 16)
#define NBLK   (TOKENS / MT)       // 256 = one block per CU
#define CK     128                 // k floats per chunk
#define NCH    (HIDDEN / CK)       // 16
#define XCB    8192                // x bytes per wave per chunk (16 rows x 512 B)
#define BUFB   65536               // bytes per dbuf half: x 32KB + B 32KB

#define GATES_OFF (TOKENS * 2)
#define SEL_OFF   (GATES_OFF + TOKENS * NEXP)
#define Z_OFF     (SEL_OFF + TOKENS * 2)

#define WIMG_BYTES (NEXP * HIDDEN * 2 * 2)   // 512 KB fp16 wh+wl fragment image

typedef __attribute__((ext_vector_type(8))) _Float16 f16x8;
typedef __attribute__((ext_vector_type(4))) float    f32x4;

__device__ __forceinline__ float wave_sum64(float v) {
    #pragma unroll
    for (int s = 1; s < 64; s <<= 1) v += __shfl_xor(v, s, 64);
    return v;
}

// direct global->LDS DMA, 16 B per lane (dest = wave-uniform base + lane*16)
__device__ __forceinline__ void dma16(const void* g, void* l) {
    __builtin_amdgcn_global_load_lds(
        (const __attribute__((address_space(1))) unsigned int*)g,
        (__attribute__((address_space(3))) unsigned int*)l, 16, 0, 0);
}

// ---------------------------------------------------------------------------
// Setup: w [64,2048] fp32 -> fp16 (hi, lo*4096) fragment image. [verified R3]
// ---------------------------------------------------------------------------
__global__ __launch_bounds__(256) void wconvert(
    const float* __restrict__ w, uint4* __restrict__ wimg)
{
    const int s = blockIdx.x * 256 + threadIdx.x;     // 0..32767
    const int c    = s >> 10;
    const int r    = s & 1023;
    const int l    = r & 63;
    const int nt   = (r >> 6) & 1;
    const int kh   = (r >> 7) & 1;
    const int term = (r >> 8) & 1;
    const int eh   = (r >> 9) & 1;
    const int e = eh * 32 + nt * 16 + (l & 15);
    const int k = c * 64 + kh * 32 + (l >> 4) * 8;

    const float* src = w + (size_t)e * HIDDEN + k;
    union { _Float16 f[8]; uint4 u; } o;
    #pragma unroll
    for (int j = 0; j < 8; ++j) {
        const float v = src[j];
        const _Float16 h = (_Float16)v;
        o.f[j] = (term == 0) ? h : (_Float16)((v - (float)h) * 4096.f);
    }
    wimg[s] = o.u;
}

// fp32 -> (hi, lo*4096) fp16x8 split of 8 floats [verified R3]
__device__ __forceinline__ void cvt_split(const float4 a, const float4 b,
                                          f16x8& hi, f16x8& lo) {
    union { _Float16 f[8]; f16x8 v; } H, L;
    #pragma unroll
    for (int j = 0; j < 4; ++j) {
        const float s0 = (&a.x)[j];
        const float s1 = (&b.x)[j];
        const _Float16 h0 = (_Float16)s0;
        const _Float16 h1 = (_Float16)s1;
        H.f[j]     = h0;
        H.f[j + 4] = h1;
        L.f[j]     = (_Float16)((s0 - (float)h0) * 4096.f);
        L.f[j + 4] = (_Float16)((s1 - (float)h1) * 4096.f);
    }
    hi = H.v; lo = L.v;
}

// ---------------------------------------------------------------------------
// R9: B-in-LDS shared staging. R4-R8 post-mortem: dominant traffic was B
// RE-FETCH -- every block re-read the whole 512KB wimg through the L1-miss
// path with register-destined (compiler-sunk, low-MLP) loads: 1024x512KB =
// 512MB -> the 73-100us plateau regardless of loop structure. Fix: 256
// blocks (1/CU), MT=64, 4 waves; B chunk staged ONCE per block into LDS via
// global_load_lds and shared by all 4 waves (B traffic 512->128MB); x also
// DMA-staged (m97: DMA sustains ~64B/cyc/CU vs ~8 lines/wave for sunk reg
// loads). 16 chunks of CK=128: stage(c+1) -> compute(c) -> __syncthreads
// (T3 minimal 2-phase; DMA flies under compute, barrier drains residual).
// x-LDS layout + A-read = R8-verified [slab64B][kg][row][16B] mapping; B-LDS
// = verbatim wimg slots (contiguous 1KB ds_read_b128, conflict-free);
// routing epilogue = R8-verified in-register scheme (16-wide shuffles).
// ---------------------------------------------------------------------------
__global__ __launch_bounds__(256, 1) void router_main(
    const float* __restrict__ x, const uint4* __restrict__ wimg,
    float* __restrict__ out, float* __restrict__ zpartial)
{
    __shared__ __align__(16) unsigned char smem[2 * BUFB];   // 128 KB
    __shared__ float zred[4];

    const int tid  = threadIdx.x;
    const int wv   = __builtin_amdgcn_readfirstlane(tid >> 6);
    const int lane = tid & 63;
    const int rowr = lane & 15;          // token row within wave tile / frag row
    const int kg   = lane >> 4;          // k-group 0..3
    const int t0b  = blockIdx.x * MT;

    // x DMA source: lane (kg,rowr) fetches row t0b+wv*16+rowr, 16B piece kg of
    // each 64B slab. Call j of chunk c covers row-bytes [c*512 + j*64, +64).
    const float* xq = x + (size_t)(t0b + wv * 16 + rowr) * HIDDEN + kg * 4;
    // B DMA source: per-lane slot pointer into wimg
    const uint4* wB = wimg + lane;

    f32x4 acc0[4], acc1[4];
    #pragma unroll
    for (int g = 0; g < 4; ++g) { acc0[g] = (f32x4)0.f; acc1[g] = (f32x4)0.f; }

    // ---- stage chunk 0 into buf 0 ----
    {
        unsigned char* xd = smem + wv * XCB;
        #pragma unroll
        for (int j = 0; j < 8; ++j)
            dma16(xq + j * 16, xd + j * 1024);
        unsigned char* bd = smem + 32768;
        #pragma unroll
        for (int i = 0; i < 8; ++i) {
            const int m = wv * 8 + i;
            dma16(wB + m * 64, bd + m * 1024);
        }
    }
    __syncthreads();   // drains DMA(0), publishes buf0

    #pragma unroll 2
    for (int c = 0; c < NCH; ++c) {
        const int buf = c & 1;

        // ---- stage chunk c+1 into the other half (flies under compute) ----
        if (c + 1 < NCH) {
            unsigned char* xd = smem + (buf ^ 1) * BUFB + wv * XCB;
            #pragma unroll
            for (int j = 0; j < 8; ++j)
                dma16(xq + (c + 1) * CK + j * 16, xd + j * 1024);
            unsigned char* bd = smem + (buf ^ 1) * BUFB + 32768;
            #pragma unroll
            for (int i = 0; i < 8; ++i) {
                const int m = wv * 8 + i;
                dma16(wB + (size_t)(c + 1) * 2048 + m * 64, bd + m * 1024);
            }
        }

        // ---- compute 4 MFMA steps (32k each) from buf ----
        const unsigned char* xb = smem + buf * BUFB + wv * XCB + kg * 512 + rowr * 16;
        const unsigned char* bb = smem + buf * BUFB + 32768;
        #pragma unroll
        for (int s = 0; s < 4; ++s) {
            const int pb = ((s >> 1) * 1024 + (s & 1) * 128 + lane) * 16;
            f16x8 bh[4], bl[4];
            bh[0] = *(const f16x8*)(bb + pb);              // e 0..15  hi
            bh[1] = *(const f16x8*)(bb + pb + 64 * 16);    // e 16..31 hi
            bh[2] = *(const f16x8*)(bb + pb + 512 * 16);   // e 32..47 hi
            bh[3] = *(const f16x8*)(bb + pb + 576 * 16);   // e 48..63 hi
            bl[0] = *(const f16x8*)(bb + pb + 256 * 16);
            bl[1] = *(const f16x8*)(bb + pb + 320 * 16);
            bl[2] = *(const f16x8*)(bb + pb + 768 * 16);
            bl[3] = *(const f16x8*)(bb + pb + 832 * 16);

            const float4 va = *(const float4*)(xb + s * 2048);
            const float4 vb = *(const float4*)(xb + s * 2048 + 256);
            f16x8 Ah, Al;
            cvt_split(va, vb, Ah, Al);
            #pragma unroll
            for (int g = 0; g < 4; ++g) {
                acc0[g] = __builtin_amdgcn_mfma_f32_16x16x32_f16(Ah, bh[g], acc0[g], 0, 0, 0);
                acc1[g] = __builtin_amdgcn_mfma_f32_16x16x32_f16(Ah, bl[g], acc1[g], 0, 0, 0);
                acc1[g] = __builtin_amdgcn_mfma_f32_16x16x32_f16(Al, bh[g], acc1[g], 0, 0, 0);
            }
        }

        __syncthreads();   // drains DMA(c+1); guards buf WAR for next iter
    }

    // ---- in-register routing [R8-verified]: lane group kg routes tokens
    // kg*4+r of this wave's 16; expert e = g*16 + rowr, 4 vals/lane.
    float zsum = 0.f;
    #pragma unroll
    for (int r = 0; r < 4; ++r) {
        const int t = wv * 16 + kg * 4 + r;       // block-local token
        float v[4]; int e[4];
        #pragma unroll
        for (int g = 0; g < 4; ++g) {
            v[g] = acc0[g][r] + acc1[g][r] * (1.f / 4096.f);
            e[g] = g * 16 + rowr;
        }

        float bv = v[0]; int bi = e[0];
        #pragma unroll
        for (int g = 1; g < 4; ++g)
            if (v[g] > bv) { bv = v[g]; bi = e[g]; }
        #pragma unroll
        for (int st = 1; st < 16; st <<= 1) {
            const float ov = __shfl_xor(bv, st, 64);
            const int   oi = __shfl_xor(bi, st, 64);
            if (ov > bv || (ov == bv && oi < bi)) { bv = ov; bi = oi; }
        }
        const float max1 = bv; const int s1 = bi;

        float e1[4], se = 0.f, sm1 = 0.f;
        #pragma unroll
        for (int g = 0; g < 4; ++g) {
            e1[g] = expf(v[g] - max1);
            se += e1[g];
            const bool m1 = (max1 - v[g]) > 0.02f * fmaxf(fabsf(v[g]), max1);
            sm1 += m1 ? 0.f : e1[g];
        }
        #pragma unroll
        for (int st = 1; st < 16; st <<= 1) {
            se  += __shfl_xor(se, st, 64);
            sm1 += __shfl_xor(sm1, st, 64);
        }

        #pragma unroll
        for (int g = 0; g < 4; ++g)
            out[GATES_OFF + (size_t)(t0b + t) * NEXP + e[g]] = e1[g] / se;

        const float lse = max1 + logf(se);
        if (rowr == 0) zsum += lse * lse;

        float bv2 = (e[0] == s1) ? -INFINITY : v[0]; int bi2 = e[0];
        #pragma unroll
        for (int g = 1; g < 4; ++g) {
            const float cv = (e[g] == s1) ? -INFINITY : v[g];
            if (cv > bv2) { bv2 = cv; bi2 = e[g]; }
        }
        #pragma unroll
        for (int st = 1; st < 16; st <<= 1) {
            const float ov = __shfl_xor(bv2, st, 64);
            const int   oi = __shfl_xor(bi2, st, 64);
            if (ov > bv2 || (ov == bv2 && oi < bi2)) { bv2 = ov; bi2 = oi; }
        }
        const float max2 = bv2; const int s2 = bi2;

        float sm2 = 0.f;
        #pragma unroll
        for (int g = 0; g < 4; ++g) {
            const bool m2 = (max2 - v[g]) > 0.02f * fmaxf(fabsf(v[g]), max2);
            sm2 += (m2 || e[g] == s1) ? 0.f : expf(v[g] - max2);
        }
        #pragma unroll
        for (int st = 1; st < 16; st <<= 1)
            sm2 += __shfl_xor(sm2, st, 64);

        if (rowr == 0) {
            const size_t trow = (size_t)(t0b + t) * 2;
            out[trow + 0] = 1.f / sm1;
            out[trow + 1] = 1.f / sm2;
            out[SEL_OFF + trow + 0] = (float)s1;
            out[SEL_OFF + trow + 1] = (float)s2;
        }
    }

    const float zt = wave_sum64(zsum);
    if (lane == 0) zred[wv] = zt;
    __syncthreads();
    if (tid == 0)
        zpartial[blockIdx.x] = zred[0] + zred[1] + zred[2] + zred[3];
}

__global__ __launch_bounds__(256) void zfinal(
    const float* __restrict__ zpartial, float* __restrict__ out)
{
    const int tid = threadIdx.x;                 // 256 partials, 256 threads
    float v = zpartial[tid];
    v = wave_sum64(v);
    __shared__ float red[4];
    if ((tid & 63) == 0) red[tid >> 6] = v;
    __syncthreads();
    if (tid == 0) {
        const float tot = red[0] + red[1] + red[2] + red[3];
        out[Z_OFF] = 0.001f * (tot / (float)TOKENS);
    }
}

extern "C" void kernel_launch(void* const* d_in, const int* in_sizes, int n_in,
                              void* d_out, int out_size, void* d_ws, size_t ws_size,
                              hipStream_t stream) {
    const float* x = (const float*)d_in[0];   // [16384, 2048] fp32
    const float* w = (const float*)d_in[1];   // [64, 2048] fp32
    float* out = (float*)d_out;               // mult(32768) | gates(1048576) | sel(32768) | z(1)

    uint4* wimg     = (uint4*)d_ws;                               // 512 KB
    float* zpartial = (float*)((char*)d_ws + WIMG_BYTES);         // 256 floats

    wconvert<<<128, 256, 0, stream>>>(w, wimg);
    router_main<<<NBLK, 256, 0, stream>>>(x, wimg, out, zpartial);
    zfinal<<<1, 256, 0, stream>>>(zpartial, out);
}